// Round 6
// baseline (1026.717 us; speedup 1.0000x reference)
//
#include <hip/hip_runtime.h>
#include <cmath>

#define B_    8
#define T_    4096
#define D_    256
#define M_    1024
#define L_    4102     // T-1+CTX
#define LP_   4104     // padded row count for transposed ctx input
#define CTX_  7
#define NROW_ 32768    // B*T

// ---------------- workspace layout (float elements) ----------------
// r4 layout (dm region now unused but offsets kept stable). inT (bf16 hi/lo)
// at OFF_CTXN; CURT overlaps it (inT dead after conv).
constexpr size_t OFF_XT    = 0;                                  // 8,388,608
constexpr size_t OFF_CTXN  = 33554432;                           // inT hi+lo: 16,809,984 ushorts
constexpr size_t OFF_CURT  = 33554432;                           // [256][32768]
constexpr size_t OFF_CTXO  = OFF_CTXN + (size_t)B_ * D_ * LP_;   // 41,959,424
constexpr size_t OFF_CUR2  = OFF_CTXO + (size_t)B_ * D_ * T_;    // 50,348,032
constexpr size_t OFF_SOFT  = OFF_CUR2 + NROW_;                   // 4096 (4 replicas)
constexpr size_t OFF_HIST  = OFF_SOFT + 4096;
constexpr size_t OFF_SUMSQ = OFF_HIST + 1024;                    // 16
constexpr size_t OFF_ESQ   = OFF_SUMSQ + 16;
constexpr size_t OFF_IDX   = OFF_ESQ + 1024;
constexpr size_t OFF_ET    = OFF_IDX + NROW_;                    // [256][1024]
constexpr size_t OFF_W1T   = OFF_ET + 262144;                    // [512][256]
constexpr size_t OFF_W2T   = OFF_W1T + 131072;
constexpr size_t OFF_WCT   = OFF_W2T + 131072;                   // WPF: 917,504 ushorts
constexpr size_t OFF_P     = OFF_WCT + 458752;                   // [1024][256]

using s16x8 = __attribute__((ext_vector_type(8))) short;
using f32x4 = __attribute__((ext_vector_type(4))) float;

__device__ __forceinline__ ushort bf16rne(float f) {
  uint u = __float_as_uint(f);
  u += 0x7fffu + ((u >> 16) & 1u);
  return (ushort)(u >> 16);
}
__device__ __forceinline__ float bf16tof(ushort h) {
  return __uint_as_float((uint)h << 16);
}

// ---------------- prep: 3 transposes + conv-weight bf16-split pack + emb rownorm + x sumsq ----------------
// WPF layout: [K8 = h*32 + i/8][part hi/lo][o 0..255][8 bf16 elems e: i = (K8%32)*8+e]
__global__ __launch_bounds__(256) void k_prep(const float* __restrict__ emb,
                                              const float* __restrict__ wf1,
                                              const float* __restrict__ wf2,
                                              const float* __restrict__ wctx,
                                              const float* __restrict__ x,
                                              float* __restrict__ ET,
                                              float* __restrict__ W1T,
                                              float* __restrict__ W2T,
                                              ushort* __restrict__ WPF,
                                              float* __restrict__ esq,
                                              float* __restrict__ sumsq) {
  const int id = blockIdx.x;
  if (id < 512) {
    __shared__ float tile[32][33];
    const int tx = threadIdx.x & 31, ty = threadIdx.x >> 5;
    const float* src; float* dst; int R, C, c0, r0;
    if (id < 256)      { src = emb;  dst = ET;  R = 1024; C = 256;  c0 = (id & 7) << 5;  r0 = (id >> 3) << 5; }
    else if (id < 384) { const int r = id - 256; src = wf1; dst = W1T; R = 256; C = 512; c0 = (r & 15) << 5; r0 = (r >> 4) << 5; }
    else               { const int r = id - 384; src = wf2; dst = W2T; R = 256; C = 512; c0 = (r & 15) << 5; r0 = (r >> 4) << 5; }
    for (int rr = ty; rr < 32; rr += 8) {
      const int rI = r0 + rr, cI = c0 + tx;
      tile[rr][tx] = (rI < R && cI < C) ? src[(size_t)rI * C + cI] : 0.f;
    }
    __syncthreads();
    for (int rr = ty; rr < 32; rr += 8) {
      const int cI = c0 + rr, rI = r0 + tx;
      if (cI < C && rI < R) dst[(size_t)cI * R + rI] = tile[tx][rr];
    }
  } else if (id < 736) {
    // weight pack: block = one K8 octet (h, i-octet j), thread = o
    const int K8 = id - 512;              // 0..223
    const int h = K8 >> 5, j = K8 & 31;
    const int o = threadIdx.x;
    uint hp[4], lp[4];
    #pragma unroll
    for (int e2 = 0; e2 < 4; ++e2) {
      ushort hs[2], ls[2];
      #pragma unroll
      for (int k = 0; k < 2; ++k) {
        const int i = (j << 3) + (e2 << 1) + k;
        const float v = wctx[(size_t)o * 1792 + (size_t)i * 7 + h];   // w_ctx[o][i][h]
        const ushort hb = bf16rne(v);
        hs[k] = hb;
        ls[k] = bf16rne(v - bf16tof(hb));
      }
      hp[e2] = (uint)hs[0] | ((uint)hs[1] << 16);
      lp[e2] = (uint)ls[0] | ((uint)ls[1] << 16);
    }
    uint4* W = (uint4*)WPF;
    W[(size_t)(K8 * 2) * 256 + o]     = make_uint4(hp[0], hp[1], hp[2], hp[3]);
    W[(size_t)(K8 * 2 + 1) * 256 + o] = make_uint4(lp[0], lp[1], lp[2], lp[3]);
  } else if (id < 992) {
    const int row = ((id - 736) << 2) + (threadIdx.x >> 6);
    const int lane = threadIdx.x & 63;
    const float4 v = ((const float4*)emb)[((size_t)row << 6) + lane];
    float s = v.x * v.x + v.y * v.y + v.z * v.z + v.w * v.w;
    #pragma unroll
    for (int off = 32; off; off >>= 1) s += __shfl_down(s, off, 64);
    if (lane == 0) esq[row] = s;
  } else {
    const int chunk = id - 992;            // 0..511
    const int b = chunk >> 6, sub = chunk & 63;
    const float4* xb = (const float4*)(x + (size_t)b * T_ * D_);
    const int N4 = (T_ - 1) * D_ / 4;
    float s = 0.f;
    for (int j = sub * 256 + threadIdx.x; j < N4; j += 64 * 256) {
      float4 v = xb[j];
      s += v.x * v.x + v.y * v.y + v.z * v.z + v.w * v.w;
    }
    #pragma unroll
    for (int off = 32; off; off >>= 1) s += __shfl_down(s, off, 64);
    __shared__ float red[4];
    const int lane = threadIdx.x & 63, wv = threadIdx.x >> 6;
    if (lane == 0) red[wv] = s;
    __syncthreads();
    if (threadIdx.x == 0) atomicAdd(&sumsq[b], (red[0] + red[1]) + (red[2] + red[3]));
  }
}

// ---------------- noisy ctx input: transposed bf16 hi/lo inT[b][tau][i] (+ xT fp32) ----------------
__global__ __launch_bounds__(256) void k_noisy(const float* __restrict__ x,
                                               const float* __restrict__ noise,
                                               const int* __restrict__ epo,
                                               const float* __restrict__ sumsq,
                                               ushort* __restrict__ inT,
                                               float* __restrict__ xT) {
  const int b = blockIdx.z;
  const int i0 = blockIdx.y << 5;
  const int tau0 = blockIdx.x << 5;
  const int tx = threadIdx.x & 31, ty = threadIdx.x >> 5;
  __shared__ float xt[32][33];   // [r][c]: x[b][tau0-7+r][i0+c] (0 outside)
  __shared__ float nz[32][33];   // [i_r][tau_r]
  const int tr0 = tau0 - CTX_;
  for (int r = ty; r < 32; r += 8) {
    const int t = tr0 + r;
    xt[r][tx] = (t >= 0 && t < T_) ? x[((size_t)b * T_ + t) * D_ + i0 + tx] : 0.f;
  }
  for (int r = ty; r < 32; r += 8) {
    const int tau = tau0 + tx;
    nz[r][tx] = (tau < L_) ? noise[((size_t)b * D_ + i0 + r) * L_ + tau] : 0.f;
  }
  __syncthreads();
  const float scale = sqrtf(sumsq[b] * (1.0f / (256.0f * 4102.0f)));
  const float coef = 0.5f * powf(0.5f, (float)epo[0] * 0.1f) * scale;
  for (int r = ty; r < 32; r += 8) {
    const int i = i0 + r;
    const int tau = tau0 + tx;
    const float xv = xt[tx][r];
    if (tau >= CTX_ && tau < T_ + CTX_)
      xT[((size_t)b * D_ + i) * T_ + (tau - CTX_)] = xv;
  }
  if (threadIdx.x < 128) {
    const int tau_r = threadIdx.x >> 2, jl = threadIdx.x & 3;
    const int tau = tau0 + tau_r;
    if (tau < L_) {
      uint hp[4], lp[4];
      #pragma unroll
      for (int e2 = 0; e2 < 4; ++e2) {
        ushort hs[2], ls[2];
        #pragma unroll
        for (int k = 0; k < 2; ++k) {
          const int ir = (jl << 3) + (e2 << 1) + k;
          const float v = coef * nz[ir][tau_r] + xt[tau_r][ir];
          const ushort hb = bf16rne(v);
          hs[k] = hb;
          ls[k] = bf16rne(v - bf16tof(hb));
        }
        hp[e2] = (uint)hs[0] | ((uint)hs[1] << 16);
        lp[e2] = (uint)ls[0] | ((uint)ls[1] << 16);
      }
      const int j = (i0 >> 3) + jl;
      const int jsw = j ^ (tau & 7);
      ushort* dst = inT + ((size_t)b * LP_ + tau) * 256 + (jsw << 3);
      *(uint4*)dst = make_uint4(hp[0], hp[1], hp[2], hp[3]);
      *(uint4*)(dst + (size_t)B_ * LP_ * 256) = make_uint4(lp[0], lp[1], lp[2], lp[3]);
    }
  }
}

// ---------------- conv via split-bf16 MFMA ----------------
__global__ __launch_bounds__(256, 2) void k_convm(const ushort* __restrict__ WPF,
                                                  const ushort* __restrict__ inT,
                                                  float* __restrict__ ctxo) {
  const int t0 = blockIdx.x << 6;
  const int b  = blockIdx.y;
  const int tid = threadIdx.x;
  const int lane = tid & 63;
  const int wv = tid >> 6;             // wave id -> o-base = wv*64
  const int ln = lane & 15, lg = lane >> 4;
  __shared__ ushort sB[2 * 72 * 256];  // [part][row 0..71][256 i], octet-swizzled
  {
    const size_t rb = ((size_t)b * LP_ + t0) * 256;
    const uint4* s4h = (const uint4*)(inT + rb);
    const uint4* s4l = (const uint4*)(inT + (size_t)B_ * LP_ * 256 + rb);
    uint4* d4 = (uint4*)sB;
    for (int q = tid; q < 2304; q += 256) d4[q] = s4h[q];
    for (int q = tid; q < 2304; q += 256) d4[2304 + q] = s4l[q];
  }
  __syncthreads();

  const f32x4 fz = {0.f, 0.f, 0.f, 0.f};
  f32x4 acc[4][4];
  #pragma unroll
  for (int i = 0; i < 4; ++i)
    #pragma unroll
    for (int j = 0; j < 4; ++j) acc[i][j] = fz;

  const ushort* wp = WPF + ((size_t)lg * 512 + (wv << 6) + ln) * 8;

  #pragma unroll 1
  for (int h = 0; h < 7; ++h) {
    #pragma unroll 1
    for (int js = 0; js < 8; ++js) {
      const int K8b = (h << 5) + (js << 2);
      s16x8 Af[2][4];
      #pragma unroll
      for (int to = 0; to < 4; ++to) {
        const ushort* ap = wp + (size_t)(K8b * 512 + (to << 4)) * 8;
        Af[0][to] = *(const s16x8*)ap;            // hi
        Af[1][to] = *(const s16x8*)(ap + 2048);   // lo (+256 entries)
      }
      s16x8 Bf[2][4];
      #pragma unroll
      for (int tt = 0; tt < 4; ++tt) {
        const int r = (tt << 4) + ln + h;
        const int jsw = ((js << 2) + lg) ^ (r & 7);
        const int e0 = r * 256 + (jsw << 3);
        Bf[0][tt] = *(const s16x8*)&sB[e0];
        Bf[1][tt] = *(const s16x8*)&sB[18432 + e0];
      }
      #pragma unroll
      for (int to = 0; to < 4; ++to)
        #pragma unroll
        for (int tt = 0; tt < 4; ++tt) {
          acc[to][tt] = __builtin_amdgcn_mfma_f32_16x16x32_bf16(Af[0][to], Bf[0][tt], acc[to][tt], 0, 0, 0);
          acc[to][tt] = __builtin_amdgcn_mfma_f32_16x16x32_bf16(Af[0][to], Bf[1][tt], acc[to][tt], 0, 0, 0);
          acc[to][tt] = __builtin_amdgcn_mfma_f32_16x16x32_bf16(Af[1][to], Bf[0][tt], acc[to][tt], 0, 0, 0);
        }
    }
  }
  float* cb = ctxo + ((size_t)b * 256 + (wv << 6)) * T_ + t0;
  #pragma unroll
  for (int to = 0; to < 4; ++to)
    #pragma unroll
    for (int tt = 0; tt < 4; ++tt)
      #pragma unroll
      for (int rg = 0; rg < 4; ++rg) {
        const int o_loc = (to << 4) + (lg << 2) + rg;
        cb[(size_t)o_loc * T_ + (tt << 4) + ln] = acc[to][tt][rg];
      }
}

// ---------------- shared GEMM helpers (fp32 path) ----------------
__device__ __forceinline__ void stage16x128(float* __restrict__ dst,
                                            const float* __restrict__ src,
                                            const int gstride, const int tid) {
  #pragma unroll
  for (int p = 0; p < 2; ++p) {
    const int q = p * 256 + tid;
    const int r = q >> 5, c = (q & 31) << 2;
    *(float4*)&dst[(r << 7) + c] = *(const float4*)&src[(size_t)r * gstride + c];
  }
}

__device__ __forceinline__ void gemm16s(const float* __restrict__ sA,
                                        const float* __restrict__ sB,
                                        const int ay, const int bx4,
                                        float acc[8][8]) {
  #pragma unroll 4
  for (int c = 0; c < 16; ++c) {
    const float4 a0 = *(const float4*)&sA[(c << 7) + ay];
    const float4 a1 = *(const float4*)&sA[(c << 7) + ay + 4];
    const float4 b0 = *(const float4*)&sB[(c << 7) + bx4];
    const float4 b1 = *(const float4*)&sB[(c << 7) + bx4 + 64];
    const float av[8] = {a0.x, a0.y, a0.z, a0.w, a1.x, a1.y, a1.z, a1.w};
    const float bv[8] = {b0.x, b0.y, b0.z, b0.w, b1.x, b1.y, b1.z, b1.w};
    #pragma unroll
    for (int i = 0; i < 8; ++i)
      #pragma unroll
      for (int j = 0; j < 8; ++j)
        acc[i][j] = fmaf(av[i], bv[j], acc[i][j]);
  }
}

// ---------------- fuse1 -> curT[o][row] + cur2[row]  (r1-exact) ----------------
__global__ __launch_bounds__(256) void k_fuse1(const float* __restrict__ xT,
                                               const float* __restrict__ ctxo,
                                               const float* __restrict__ w1T,
                                               const float* __restrict__ a1,
                                               float* __restrict__ curT,
                                               float* __restrict__ cur2) {
  const int bk = blockIdx.x;
  const int b = bk >> 5;
  const int t0 = (bk & 31) << 7;
  const int o0 = blockIdx.y << 7;
  const int tid = threadIdx.x;
  const int tx = tid & 15, ty = tid >> 4;
  const int ox = ty << 3, tp4 = tx << 2;
  __shared__ float smem[4096];
  float* sW = smem;
  float* sX = smem + 2048;
  float acc[8][8] = {};
  for (int cc = 0; cc < 512; cc += 16) {
    __syncthreads();
    stage16x128(sW, w1T + (size_t)cc * 256 + o0, 256, tid);
    const float* xsrc = (cc < 256)
        ? xT + ((size_t)b * D_ + cc) * T_ + t0
        : ctxo + ((size_t)b * D_ + (cc - 256)) * T_ + t0;
    stage16x128(sX, xsrc, T_, tid);
    __syncthreads();
    gemm16s(sW, sX, ox, tp4, acc);
  }
  const float alpha = a1[0];
  const size_t row0 = (size_t)b * T_ + t0;
  float part[8] = {};
  #pragma unroll
  for (int oo = 0; oo < 8; ++oo) {
    #pragma unroll
    for (int j = 0; j < 8; ++j) {
      float v = acc[oo][j];
      v = (v >= 0.f) ? v : alpha * v;
      acc[oo][j] = v;
      part[j] = fmaf(v, v, part[j]);
    }
    const float4 v0 = {acc[oo][0], acc[oo][1], acc[oo][2], acc[oo][3]};
    const float4 v1 = {acc[oo][4], acc[oo][5], acc[oo][6], acc[oo][7]};
    float* dst = curT + (size_t)(o0 + ox + oo) * NROW_ + row0;
    *(float4*)(dst + tp4) = v0;
    *(float4*)(dst + tp4 + 64) = v1;
  }
  __syncthreads();
  float* red = smem;
  #pragma unroll
  for (int j = 0; j < 4; ++j) {
    red[(tp4 + j) * 17 + ty] = part[j];
    red[(tp4 + 64 + j) * 17 + ty] = part[4 + j];
  }
  __syncthreads();
  if (tid < 128) {
    float s = 0.f;
    #pragma unroll
    for (int k = 0; k < 16; ++k) s += red[tid * 17 + k];
    atomicAdd(&cur2[row0 + tid], s);
  }
}

// ---------------- P[m][o] = sum_c E[m][c] * wf2[o][c]  (c<256 half) ----------------
__global__ __launch_bounds__(256) void k_pmm(const float* __restrict__ ET,
                                             const float* __restrict__ w2T,
                                             float* __restrict__ P) {
  const int m0 = blockIdx.x << 7;
  const int o0 = blockIdx.y << 7;
  const int tid = threadIdx.x;
  const int tx = tid & 15, ty = tid >> 4;
  const int my = ty << 3, ox4 = tx << 2;
  __shared__ float smem[4096];
  float* sM = smem;
  float* sW = smem + 2048;
  float acc[8][8] = {};
  for (int cc = 0; cc < 256; cc += 16) {
    __syncthreads();
    stage16x128(sM, ET + (size_t)cc * M_ + m0, M_, tid);
    stage16x128(sW, w2T + (size_t)cc * 256 + o0, 256, tid);
    __syncthreads();
    gemm16s(sM, sW, my, ox4, acc);
  }
  #pragma unroll
  for (int mm = 0; mm < 8; ++mm) {
    const float4 v0 = {acc[mm][0], acc[mm][1], acc[mm][2], acc[mm][3]};
    const float4 v1 = {acc[mm][4], acc[mm][5], acc[mm][6], acc[mm][7]};
    float* dst = P + (size_t)(m0 + my + mm) * 256 + o0;
    *(float4*)(dst + ox4) = v0;
    *(float4*)(dst + ox4 + 64) = v1;
  }
}

// ---------------- fused dist+softmax: dm never materialized ----------------
// Block: 32 rows x full M=1024, 4 waves; wave w owns rows r0+8w..+7.
// Lane holds m = (lane<<2) + (q<<8) + jj (q=s>>2, jj=s&3) -- identical to
// k_soft's mapping. GEMM accumulation: fmaf chain over c=0..255 ascending,
// bit-identical to gemm16s tiling -> dm bits identical to the passing r4 run
// -> argmax/hist/idx outputs bit-identical. Only soft4 sum order differs
// (output 2, mean over 32768 rows -- robust).
__global__ __launch_bounds__(256, 2) void k_dsoft(const float* __restrict__ curT,
                                                  const float* __restrict__ ET,
                                                  const float* __restrict__ cur2,
                                                  const float* __restrict__ esq,
                                                  const float* __restrict__ gu,
                                                  float* __restrict__ soft4,
                                                  unsigned* __restrict__ hist,
                                                  int* __restrict__ idxi,
                                                  float* __restrict__ idxf) {
  const int tid = threadIdx.x;
  const int lane = tid & 63, wv = tid >> 6;
  const int r0 = blockIdx.x << 5;
  __shared__ float sC[16 * 32];      // [c][r]
  __shared__ float sE[16 * 1024];    // [c][m]
  __shared__ float accS[1024];
  __shared__ unsigned histS[1024];
  for (int j = tid; j < 1024; j += 256) { accS[j] = 0.f; histS[j] = 0u; }

  float acc[8][16];                  // [rr][s]; m = (lane<<2)+((s>>2)<<8)+(s&3)
  #pragma unroll
  for (int rr = 0; rr < 8; ++rr)
    #pragma unroll
    for (int s = 0; s < 16; ++s) acc[rr][s] = 0.f;

  for (int cc = 0; cc < 256; cc += 16) {
    __syncthreads();
    if (tid < 128) {
      const int c = tid >> 3, o = (tid & 7) << 2;
      *(float4*)&sC[c * 32 + o] = *(const float4*)&curT[(size_t)(cc + c) * NROW_ + r0 + o];
    }
    #pragma unroll
    for (int p = 0; p < 16; ++p) {
      const int q = p * 256 + tid;
      const int c = q >> 8, m = (q & 255) << 2;
      *(float4*)&sE[c * 1024 + m] = *(const float4*)&ET[(size_t)(cc + c) * M_ + m];
    }
    __syncthreads();
    #pragma unroll 4
    for (int c = 0; c < 16; ++c) {
      float a[8];
      *(float4*)&a[0] = *(const float4*)&sC[c * 32 + (wv << 3)];
      *(float4*)&a[4] = *(const float4*)&sC[c * 32 + (wv << 3) + 4];
      float bb[16];
      #pragma unroll
      for (int q = 0; q < 4; ++q)
        *(float4*)&bb[q << 2] = *(const float4*)&sE[c * 1024 + (q << 8) + (lane << 2)];
      #pragma unroll
      for (int rr = 0; rr < 8; ++rr)
        #pragma unroll
        for (int s = 0; s < 16; ++s)
          acc[rr][s] = fmaf(a[rr], bb[s], acc[rr][s]);
    }
  }

  // per-lane esq values (same m mapping)
  float e2v[16];
  #pragma unroll
  for (int q = 0; q < 4; ++q)
    *(float4*)&e2v[q << 2] = *(const float4*)&esq[(q << 8) + (lane << 2)];

  float p[16] = {};
  const int rbase = r0 + (wv << 3);
  for (int rr = 0; rr < 8; ++rr) {
    const int r = rbase + rr;
    const float c2r = cur2[r];
    float v[16];
    #pragma unroll
    for (int s = 0; s < 16; ++s)
      v[s] = -(c2r + e2v[s] - 2.0f * acc[rr][s]);
    float mx = v[0];
    #pragma unroll
    for (int s = 1; s < 16; ++s) mx = fmaxf(mx, v[s]);
    #pragma unroll
    for (int m = 32; m; m >>= 1) mx = fmaxf(mx, __shfl_xor(mx, m, 64));
    float e[16]; float sum = 0.f;
    #pragma unroll
    for (int s = 0; s < 16; ++s) { e[s] = expf(v[s] - mx); sum += e[s]; }
    #pragma unroll
    for (int m = 32; m; m >>= 1) sum += __shfl_xor(sum, m, 64);
    const float inv = 1.0f / sum;
    #pragma unroll
    for (int s = 0; s < 16; ++s) p[s] = fmaf(e[s], inv, p[s]);
    float bv = v[0]; int bi = (lane << 2);
    #pragma unroll
    for (int s = 1; s < 16; ++s) {
      const int m_ = (lane << 2) + ((s >> 2) << 8) + (s & 3);
      if (v[s] > bv) { bv = v[s]; bi = m_; }
    }
    #pragma unroll
    for (int m = 32; m; m >>= 1) {
      const float ov = __shfl_xor(bv, m, 64);
      const int oi = __shfl_xor(bi, m, 64);
      if (ov > bv || (ov == bv && oi < bi)) { bv = ov; bi = oi; }
    }
    if (lane == 0) atomicAdd(&histS[bi], 1u);
    const float4* gr = (const float4*)(gu + ((size_t)r << 10));
    float z[16];
    #pragma unroll
    for (int k = 0; k < 4; ++k) {
      const float4 u = gr[lane + (k << 6)];
      const float uu[4] = {u.x, u.y, u.z, u.w};
      #pragma unroll
      for (int j = 0; j < 4; ++j) {
        const float uc = fminf(fmaxf(uu[j], 1e-10f), 1.0f - 1e-7f);
        z[k * 4 + j] = v[k * 4 + j] - logf(-logf(uc));
      }
    }
    bv = z[0]; bi = (lane << 2);
    #pragma unroll
    for (int s = 1; s < 16; ++s) {
      const int m_ = (lane << 2) + ((s >> 2) << 8) + (s & 3);
      if (z[s] > bv) { bv = z[s]; bi = m_; }
    }
    #pragma unroll
    for (int m = 32; m; m >>= 1) {
      const float ov = __shfl_xor(bv, m, 64);
      const int oi = __shfl_xor(bi, m, 64);
      if (ov > bv || (ov == bv && oi < bi)) { bv = ov; bi = oi; }
    }
    if (lane == 0) { idxi[r] = bi; idxf[r] = (float)bi; }
  }
  #pragma unroll
  for (int s = 0; s < 16; ++s)
    atomicAdd(&accS[(lane << 2) + ((s >> 2) << 8) + (s & 3)], p[s]);
  __syncthreads();
  const int rep = (blockIdx.x & 3) << 10;
  for (int j = tid; j < 1024; j += 256) {
    atomicAdd(&soft4[rep + j], accS[j]);
    const unsigned h = histS[j];
    if (h) atomicAdd(&hist[j], h);
  }
}

// ---------------- perplexities ----------------
__global__ __launch_bounds__(256) void k_perp(const float* __restrict__ soft4,
                                              const unsigned* __restrict__ hist,
                                              float* __restrict__ out2) {
  const int tid = threadIdx.x;
  float cp = 0.f, pp = 0.f;
  for (int m = tid; m < 1024; m += 256) {
    const float hp = (float)hist[m] * (1.0f / 32768.0f);
    cp += hp * log2f(hp + 1e-10f);
    const float q = (soft4[m] + soft4[1024 + m] + soft4[2048 + m] + soft4[3072 + m]) * (1.0f / 32768.0f);
    pp += q * log2f(q + 1e-10f);
  }
  #pragma unroll
  for (int off = 32; off; off >>= 1) {
    cp += __shfl_down(cp, off, 64);
    pp += __shfl_down(pp, off, 64);
  }
  __shared__ float rc[4], rp[4];
  const int lane = tid & 63, wv = tid >> 6;
  if (lane == 0) { rc[wv] = cp; rp[wv] = pp; }
  __syncthreads();
  if (tid == 0) {
    out2[0] = -((rc[0] + rc[1]) + (rc[2] + rc[3]));
    out2[1] = -((rp[0] + rp[1]) + (rp[2] + rp[3]));
  }
}

// ---------------- fuse2 via 1-plane bf16 MFMA ----------------
__global__ __launch_bounds__(256) void k_fuse2m(const float* __restrict__ ctxo,
                                                const float* __restrict__ w2T,
                                                const float* __restrict__ P,
                                                const int* __restrict__ idxi,
                                                const float* __restrict__ a2,
                                                float* __restrict__ outq) {
  const int bk = blockIdx.x;
  const int b = bk >> 6;
  const int t0 = (bk & 63) << 6;
  const int tid = threadIdx.x;
  const int lane = tid & 63, wv = tid >> 6;
  const int ln = lane & 15, lg = lane >> 4;
  const int o0w = wv << 6;
  __shared__ int idxS[64];
  if (tid < 64) idxS[tid] = idxi[(size_t)b * T_ + t0 + tid];
  __syncthreads();

  const f32x4 fz = {0.f, 0.f, 0.f, 0.f};
  f32x4 acc[4][4];   // [to][tt]
  #pragma unroll
  for (int i = 0; i < 4; ++i)
    #pragma unroll
    for (int j = 0; j < 4; ++j) acc[i][j] = fz;

  #pragma unroll 1
  for (int ks = 0; ks < 8; ++ks) {
    const int cb = (ks << 5) + (lg << 3);
    s16x8 Af[4];
    #pragma unroll
    for (int to = 0; to < 4; ++to) {
      const float* wp = w2T + (size_t)(256 + cb) * 256 + o0w + (to << 4) + ln;
      #pragma unroll
      for (int e = 0; e < 8; ++e)
        Af[to][e] = (short)bf16rne(wp[(size_t)e * 256]);
    }
    s16x8 Bf[4];
    #pragma unroll
    for (int tt = 0; tt < 4; ++tt) {
      const float* xp = ctxo + ((size_t)b * D_ + cb) * T_ + t0 + (tt << 4) + ln;
      #pragma unroll
      for (int e = 0; e < 8; ++e)
        Bf[tt][e] = (short)bf16rne(xp[(size_t)e * T_]);
    }
    #pragma unroll
    for (int to = 0; to < 4; ++to)
      #pragma unroll
      for (int tt = 0; tt < 4; ++tt)
        acc[to][tt] = __builtin_amdgcn_mfma_f32_16x16x32_bf16(Af[to], Bf[tt], acc[to][tt], 0, 0, 0);
  }

  const float alpha = a2[0];
  #pragma unroll
  for (int tt = 0; tt < 4; ++tt) {
    const int t = t0 + (tt << 4) + ln;
    const int id = idxS[(tt << 4) + ln];
    #pragma unroll
    for (int to = 0; to < 4; ++to) {
      const int ob = o0w + (to << 4) + (lg << 2);
      const float4 p4 = *(const float4*)&P[(size_t)id * 256 + ob];
      const float pv[4] = {p4.x, p4.y, p4.z, p4.w};
      float o[4];
      #pragma unroll
      for (int rg = 0; rg < 4; ++rg) {
        const float v = acc[to][tt][rg] + pv[rg];
        o[rg] = (v >= 0.f) ? v : alpha * v;
      }
      *(float4*)&outq[((size_t)b * T_ + t) * D_ + ob] = *(float4*)&o[0];
    }
  }
}

extern "C" void kernel_launch(void* const* d_in, const int* in_sizes, int n_in,
                              void* d_out, int out_size, void* d_ws, size_t ws_size,
                              hipStream_t stream) {
  (void)in_sizes; (void)n_in; (void)out_size; (void)ws_size;
  const float* x     = (const float*)d_in[0];
  const float* noise = (const float*)d_in[1];
  const float* gu    = (const float*)d_in[2];
  const int*   epo   = (const int*)d_in[3];
  const float* emb   = (const float*)d_in[4];
  const float* wctx  = (const float*)d_in[5];
  const float* wf1   = (const float*)d_in[6];
  const float* a1    = (const float*)d_in[7];
  const float* wf2   = (const float*)d_in[8];
  const float* a2    = (const float*)d_in[9];

  float* ws    = (float*)d_ws;
  float* xT    = ws + OFF_XT;
  ushort* inT  = (ushort*)(ws + OFF_CTXN);
  float* curT  = ws + OFF_CURT;
  float* ctxo  = ws + OFF_CTXO;
  float* cur2  = ws + OFF_CUR2;
  float* soft  = ws + OFF_SOFT;
  unsigned* hist = (unsigned*)(ws + OFF_HIST);
  float* sumsq = ws + OFF_SUMSQ;
  float* esq   = ws + OFF_ESQ;
  int*   idxi  = (int*)(ws + OFF_IDX);
  float* ET    = ws + OFF_ET;
  float* W1T   = ws + OFF_W1T;
  float* W2T   = ws + OFF_W2T;
  ushort* WPF  = (ushort*)(ws + OFF_WCT);
  float* P     = ws + OFF_P;

  float* outq = (float*)d_out;
  float* scal = outq + (size_t)NROW_ * D_;
  float* idxf = scal + 2;

  hipMemsetAsync(ws + OFF_CUR2, 0, (NROW_ + 4096 + 1024 + 16) * sizeof(float), stream);

  k_prep  <<<1504, 256, 0, stream>>>(emb, wf1, wf2, wctx, x, ET, W1T, W2T, WPF, esq, sumsq);
  k_noisy <<<dim3(129, 8, 8), 256, 0, stream>>>(x, noise, epo, sumsq, inT, xT);
  k_convm <<<dim3(64, 8), 256, 0, stream>>>(WPF, inT, ctxo);
  k_fuse1 <<<dim3(256, 2), 256, 0, stream>>>(xT, ctxo, W1T, a1, curT, cur2);
  k_pmm   <<<dim3(8, 2), 256, 0, stream>>>(ET, W2T, P);
  k_dsoft <<<1024, 256, 0, stream>>>(curT, ET, cur2, esq, gu, soft, hist, idxi, idxf);
  k_perp  <<<1, 256, 0, stream>>>(soft, hist, scal);
  k_fuse2m<<<512, 256, 0, stream>>>(ctxo, W2T, P, idxi, a2, outq);
}

// Round 7
// 781.423 us; speedup vs baseline: 1.3139x; 1.3139x over previous
//
#include <hip/hip_runtime.h>
#include <cmath>

#define B_    8
#define T_    4096
#define D_    256
#define M_    1024
#define L_    4102     // T-1+CTX
#define LP_   4104     // padded row count for transposed ctx input
#define CTX_  7
#define NROW_ 32768    // B*T

// ---------------- workspace layout (float elements) ----------------
constexpr size_t OFF_XT    = 0;                                  // 8,388,608
constexpr size_t OFF_CTXN  = 33554432;                           // inT hi+lo: 16,809,984 ushorts
constexpr size_t OFF_CURT  = 33554432;                           // [256][32768]
constexpr size_t OFF_CTXO  = OFF_CTXN + (size_t)B_ * D_ * LP_;   // 41,959,424
constexpr size_t OFF_CUR2  = OFF_CTXO + (size_t)B_ * D_ * T_;    // 50,348,032
constexpr size_t OFF_SOFT  = OFF_CUR2 + NROW_;                   // 4096 (4 replicas)
constexpr size_t OFF_HIST  = OFF_SOFT + 4096;
constexpr size_t OFF_SUMSQ = OFF_HIST + 1024;                    // 16
constexpr size_t OFF_ESQ   = OFF_SUMSQ + 16;
constexpr size_t OFF_IDX   = OFF_ESQ + 1024;
constexpr size_t OFF_ET    = OFF_IDX + NROW_;                    // [256][1024]
constexpr size_t OFF_W1T   = OFF_ET + 262144;                    // [512][256]
constexpr size_t OFF_W2T   = OFF_W1T + 131072;
constexpr size_t OFF_WCT   = OFF_W2T + 131072;                   // WPF: 917,504 ushorts
constexpr size_t OFF_P     = OFF_WCT + 458752;                   // [1024][256]

using s16x8 = __attribute__((ext_vector_type(8))) short;
using f32x4 = __attribute__((ext_vector_type(4))) float;

__device__ __forceinline__ ushort bf16rne(float f) {
  uint u = __float_as_uint(f);
  u += 0x7fffu + ((u >> 16) & 1u);
  return (ushort)(u >> 16);
}
__device__ __forceinline__ float bf16tof(ushort h) {
  return __uint_as_float((uint)h << 16);
}

// ---------------- prep: 3 transposes + conv-weight bf16-split pack + emb rownorm + x sumsq ----------------
// WPF layout: [K8 = h*32 + i/8][part hi/lo][o 0..255][8 bf16 elems e: i = (K8%32)*8+e]
__global__ __launch_bounds__(256) void k_prep(const float* __restrict__ emb,
                                              const float* __restrict__ wf1,
                                              const float* __restrict__ wf2,
                                              const float* __restrict__ wctx,
                                              const float* __restrict__ x,
                                              float* __restrict__ ET,
                                              float* __restrict__ W1T,
                                              float* __restrict__ W2T,
                                              ushort* __restrict__ WPF,
                                              float* __restrict__ esq,
                                              float* __restrict__ sumsq) {
  const int id = blockIdx.x;
  if (id < 512) {
    __shared__ float tile[32][33];
    const int tx = threadIdx.x & 31, ty = threadIdx.x >> 5;
    const float* src; float* dst; int R, C, c0, r0;
    if (id < 256)      { src = emb;  dst = ET;  R = 1024; C = 256;  c0 = (id & 7) << 5;  r0 = (id >> 3) << 5; }
    else if (id < 384) { const int r = id - 256; src = wf1; dst = W1T; R = 256; C = 512; c0 = (r & 15) << 5; r0 = (r >> 4) << 5; }
    else               { const int r = id - 384; src = wf2; dst = W2T; R = 256; C = 512; c0 = (r & 15) << 5; r0 = (r >> 4) << 5; }
    for (int rr = ty; rr < 32; rr += 8) {
      const int rI = r0 + rr, cI = c0 + tx;
      tile[rr][tx] = (rI < R && cI < C) ? src[(size_t)rI * C + cI] : 0.f;
    }
    __syncthreads();
    for (int rr = ty; rr < 32; rr += 8) {
      const int cI = c0 + rr, rI = r0 + tx;
      if (cI < C && rI < R) dst[(size_t)cI * R + rI] = tile[tx][rr];
    }
  } else if (id < 736) {
    // weight pack: block = one K8 octet (h, i-octet j), thread = o
    const int K8 = id - 512;              // 0..223
    const int h = K8 >> 5, j = K8 & 31;
    const int o = threadIdx.x;
    uint hp[4], lp[4];
    #pragma unroll
    for (int e2 = 0; e2 < 4; ++e2) {
      ushort hs[2], ls[2];
      #pragma unroll
      for (int k = 0; k < 2; ++k) {
        const int i = (j << 3) + (e2 << 1) + k;
        const float v = wctx[(size_t)o * 1792 + (size_t)i * 7 + h];   // w_ctx[o][i][h]
        const ushort hb = bf16rne(v);
        hs[k] = hb;
        ls[k] = bf16rne(v - bf16tof(hb));
      }
      hp[e2] = (uint)hs[0] | ((uint)hs[1] << 16);
      lp[e2] = (uint)ls[0] | ((uint)ls[1] << 16);
    }
    uint4* W = (uint4*)WPF;
    W[(size_t)(K8 * 2) * 256 + o]     = make_uint4(hp[0], hp[1], hp[2], hp[3]);
    W[(size_t)(K8 * 2 + 1) * 256 + o] = make_uint4(lp[0], lp[1], lp[2], lp[3]);
  } else if (id < 992) {
    const int row = ((id - 736) << 2) + (threadIdx.x >> 6);
    const int lane = threadIdx.x & 63;
    const float4 v = ((const float4*)emb)[((size_t)row << 6) + lane];
    float s = v.x * v.x + v.y * v.y + v.z * v.z + v.w * v.w;
    #pragma unroll
    for (int off = 32; off; off >>= 1) s += __shfl_down(s, off, 64);
    if (lane == 0) esq[row] = s;
  } else {
    const int chunk = id - 992;            // 0..511
    const int b = chunk >> 6, sub = chunk & 63;
    const float4* xb = (const float4*)(x + (size_t)b * T_ * D_);
    const int N4 = (T_ - 1) * D_ / 4;
    float s = 0.f;
    for (int j = sub * 256 + threadIdx.x; j < N4; j += 64 * 256) {
      float4 v = xb[j];
      s += v.x * v.x + v.y * v.y + v.z * v.z + v.w * v.w;
    }
    #pragma unroll
    for (int off = 32; off; off >>= 1) s += __shfl_down(s, off, 64);
    __shared__ float red[4];
    const int lane = threadIdx.x & 63, wv = threadIdx.x >> 6;
    if (lane == 0) red[wv] = s;
    __syncthreads();
    if (threadIdx.x == 0) atomicAdd(&sumsq[b], (red[0] + red[1]) + (red[2] + red[3]));
  }
}

// ---------------- noisy ctx input: transposed bf16 hi/lo inT[b][tau][i] (+ xT fp32) ----------------
__global__ __launch_bounds__(256) void k_noisy(const float* __restrict__ x,
                                               const float* __restrict__ noise,
                                               const int* __restrict__ epo,
                                               const float* __restrict__ sumsq,
                                               ushort* __restrict__ inT,
                                               float* __restrict__ xT) {
  const int b = blockIdx.z;
  const int i0 = blockIdx.y << 5;
  const int tau0 = blockIdx.x << 5;
  const int tx = threadIdx.x & 31, ty = threadIdx.x >> 5;
  __shared__ float xt[32][33];   // [r][c]: x[b][tau0-7+r][i0+c] (0 outside)
  __shared__ float nz[32][33];   // [i_r][tau_r]
  const int tr0 = tau0 - CTX_;
  for (int r = ty; r < 32; r += 8) {
    const int t = tr0 + r;
    xt[r][tx] = (t >= 0 && t < T_) ? x[((size_t)b * T_ + t) * D_ + i0 + tx] : 0.f;
  }
  for (int r = ty; r < 32; r += 8) {
    const int tau = tau0 + tx;
    nz[r][tx] = (tau < L_) ? noise[((size_t)b * D_ + i0 + r) * L_ + tau] : 0.f;
  }
  __syncthreads();
  const float scale = sqrtf(sumsq[b] * (1.0f / (256.0f * 4102.0f)));
  const float coef = 0.5f * powf(0.5f, (float)epo[0] * 0.1f) * scale;
  for (int r = ty; r < 32; r += 8) {
    const int i = i0 + r;
    const int tau = tau0 + tx;
    const float xv = xt[tx][r];
    if (tau >= CTX_ && tau < T_ + CTX_)
      xT[((size_t)b * D_ + i) * T_ + (tau - CTX_)] = xv;
  }
  if (threadIdx.x < 128) {
    const int tau_r = threadIdx.x >> 2, jl = threadIdx.x & 3;
    const int tau = tau0 + tau_r;
    if (tau < L_) {
      uint hp[4], lp[4];
      #pragma unroll
      for (int e2 = 0; e2 < 4; ++e2) {
        ushort hs[2], ls[2];
        #pragma unroll
        for (int k = 0; k < 2; ++k) {
          const int ir = (jl << 3) + (e2 << 1) + k;
          const float v = coef * nz[ir][tau_r] + xt[tau_r][ir];
          const ushort hb = bf16rne(v);
          hs[k] = hb;
          ls[k] = bf16rne(v - bf16tof(hb));
        }
        hp[e2] = (uint)hs[0] | ((uint)hs[1] << 16);
        lp[e2] = (uint)ls[0] | ((uint)ls[1] << 16);
      }
      const int j = (i0 >> 3) + jl;
      const int jsw = j ^ (tau & 7);
      ushort* dst = inT + ((size_t)b * LP_ + tau) * 256 + (jsw << 3);
      *(uint4*)dst = make_uint4(hp[0], hp[1], hp[2], hp[3]);
      *(uint4*)(dst + (size_t)B_ * LP_ * 256) = make_uint4(lp[0], lp[1], lp[2], lp[3]);
    }
  }
}

// ---------------- conv via split-bf16 MFMA ----------------
__global__ __launch_bounds__(256, 2) void k_convm(const ushort* __restrict__ WPF,
                                                  const ushort* __restrict__ inT,
                                                  float* __restrict__ ctxo) {
  const int t0 = blockIdx.x << 6;
  const int b  = blockIdx.y;
  const int tid = threadIdx.x;
  const int lane = tid & 63;
  const int wv = tid >> 6;             // wave id -> o-base = wv*64
  const int ln = lane & 15, lg = lane >> 4;
  __shared__ ushort sB[2 * 72 * 256];  // [part][row 0..71][256 i], octet-swizzled
  {
    const size_t rb = ((size_t)b * LP_ + t0) * 256;
    const uint4* s4h = (const uint4*)(inT + rb);
    const uint4* s4l = (const uint4*)(inT + (size_t)B_ * LP_ * 256 + rb);
    uint4* d4 = (uint4*)sB;
    for (int q = tid; q < 2304; q += 256) d4[q] = s4h[q];
    for (int q = tid; q < 2304; q += 256) d4[2304 + q] = s4l[q];
  }
  __syncthreads();

  const f32x4 fz = {0.f, 0.f, 0.f, 0.f};
  f32x4 acc[4][4];
  #pragma unroll
  for (int i = 0; i < 4; ++i)
    #pragma unroll
    for (int j = 0; j < 4; ++j) acc[i][j] = fz;

  const ushort* wp = WPF + ((size_t)lg * 512 + (wv << 6) + ln) * 8;

  #pragma unroll 1
  for (int h = 0; h < 7; ++h) {
    #pragma unroll 1
    for (int js = 0; js < 8; ++js) {
      const int K8b = (h << 5) + (js << 2);
      s16x8 Af[2][4];
      #pragma unroll
      for (int to = 0; to < 4; ++to) {
        const ushort* ap = wp + (size_t)(K8b * 512 + (to << 4)) * 8;
        Af[0][to] = *(const s16x8*)ap;            // hi
        Af[1][to] = *(const s16x8*)(ap + 2048);   // lo (+256 entries)
      }
      s16x8 Bf[2][4];
      #pragma unroll
      for (int tt = 0; tt < 4; ++tt) {
        const int r = (tt << 4) + ln + h;
        const int jsw = ((js << 2) + lg) ^ (r & 7);
        const int e0 = r * 256 + (jsw << 3);
        Bf[0][tt] = *(const s16x8*)&sB[e0];
        Bf[1][tt] = *(const s16x8*)&sB[18432 + e0];
      }
      #pragma unroll
      for (int to = 0; to < 4; ++to)
        #pragma unroll
        for (int tt = 0; tt < 4; ++tt) {
          acc[to][tt] = __builtin_amdgcn_mfma_f32_16x16x32_bf16(Af[0][to], Bf[0][tt], acc[to][tt], 0, 0, 0);
          acc[to][tt] = __builtin_amdgcn_mfma_f32_16x16x32_bf16(Af[0][to], Bf[1][tt], acc[to][tt], 0, 0, 0);
          acc[to][tt] = __builtin_amdgcn_mfma_f32_16x16x32_bf16(Af[1][to], Bf[0][tt], acc[to][tt], 0, 0, 0);
        }
    }
  }
  float* cb = ctxo + ((size_t)b * 256 + (wv << 6)) * T_ + t0;
  #pragma unroll
  for (int to = 0; to < 4; ++to)
    #pragma unroll
    for (int tt = 0; tt < 4; ++tt)
      #pragma unroll
      for (int rg = 0; rg < 4; ++rg) {
        const int o_loc = (to << 4) + (lg << 2) + rg;
        cb[(size_t)o_loc * T_ + (tt << 4) + ln] = acc[to][tt][rg];
      }
}

// ---------------- shared GEMM helpers (fp32 path) ----------------
__device__ __forceinline__ void stage16x128(float* __restrict__ dst,
                                            const float* __restrict__ src,
                                            const int gstride, const int tid) {
  #pragma unroll
  for (int p = 0; p < 2; ++p) {
    const int q = p * 256 + tid;
    const int r = q >> 5, c = (q & 31) << 2;
    *(float4*)&dst[(r << 7) + c] = *(const float4*)&src[(size_t)r * gstride + c];
  }
}

__device__ __forceinline__ void gemm16s(const float* __restrict__ sA,
                                        const float* __restrict__ sB,
                                        const int ay, const int bx4,
                                        float acc[8][8]) {
  #pragma unroll 4
  for (int c = 0; c < 16; ++c) {
    const float4 a0 = *(const float4*)&sA[(c << 7) + ay];
    const float4 a1 = *(const float4*)&sA[(c << 7) + ay + 4];
    const float4 b0 = *(const float4*)&sB[(c << 7) + bx4];
    const float4 b1 = *(const float4*)&sB[(c << 7) + bx4 + 64];
    const float av[8] = {a0.x, a0.y, a0.z, a0.w, a1.x, a1.y, a1.z, a1.w};
    const float bv[8] = {b0.x, b0.y, b0.z, b0.w, b1.x, b1.y, b1.z, b1.w};
    #pragma unroll
    for (int i = 0; i < 8; ++i)
      #pragma unroll
      for (int j = 0; j < 8; ++j)
        acc[i][j] = fmaf(av[i], bv[j], acc[i][j]);
  }
}

// ---------------- fuse1 -> curT[o][row] + cur2[row]  (r1-exact) ----------------
__global__ __launch_bounds__(256) void k_fuse1(const float* __restrict__ xT,
                                               const float* __restrict__ ctxo,
                                               const float* __restrict__ w1T,
                                               const float* __restrict__ a1,
                                               float* __restrict__ curT,
                                               float* __restrict__ cur2) {
  const int bk = blockIdx.x;
  const int b = bk >> 5;
  const int t0 = (bk & 31) << 7;
  const int o0 = blockIdx.y << 7;
  const int tid = threadIdx.x;
  const int tx = tid & 15, ty = tid >> 4;
  const int ox = ty << 3, tp4 = tx << 2;
  __shared__ float smem[4096];
  float* sW = smem;
  float* sX = smem + 2048;
  float acc[8][8] = {};
  for (int cc = 0; cc < 512; cc += 16) {
    __syncthreads();
    stage16x128(sW, w1T + (size_t)cc * 256 + o0, 256, tid);
    const float* xsrc = (cc < 256)
        ? xT + ((size_t)b * D_ + cc) * T_ + t0
        : ctxo + ((size_t)b * D_ + (cc - 256)) * T_ + t0;
    stage16x128(sX, xsrc, T_, tid);
    __syncthreads();
    gemm16s(sW, sX, ox, tp4, acc);
  }
  const float alpha = a1[0];
  const size_t row0 = (size_t)b * T_ + t0;
  float part[8] = {};
  #pragma unroll
  for (int oo = 0; oo < 8; ++oo) {
    #pragma unroll
    for (int j = 0; j < 8; ++j) {
      float v = acc[oo][j];
      v = (v >= 0.f) ? v : alpha * v;
      acc[oo][j] = v;
      part[j] = fmaf(v, v, part[j]);
    }
    const float4 v0 = {acc[oo][0], acc[oo][1], acc[oo][2], acc[oo][3]};
    const float4 v1 = {acc[oo][4], acc[oo][5], acc[oo][6], acc[oo][7]};
    float* dst = curT + (size_t)(o0 + ox + oo) * NROW_ + row0;
    *(float4*)(dst + tp4) = v0;
    *(float4*)(dst + tp4 + 64) = v1;
  }
  __syncthreads();
  float* red = smem;
  #pragma unroll
  for (int j = 0; j < 4; ++j) {
    red[(tp4 + j) * 17 + ty] = part[j];
    red[(tp4 + 64 + j) * 17 + ty] = part[4 + j];
  }
  __syncthreads();
  if (tid < 128) {
    float s = 0.f;
    #pragma unroll
    for (int k = 0; k < 16; ++k) s += red[tid * 17 + k];
    atomicAdd(&cur2[row0 + tid], s);
  }
}

// ---------------- P[m][o] = sum_c E[m][c] * wf2[o][c]  (c<256 half) ----------------
__global__ __launch_bounds__(256) void k_pmm(const float* __restrict__ ET,
                                             const float* __restrict__ w2T,
                                             float* __restrict__ P) {
  const int m0 = blockIdx.x << 7;
  const int o0 = blockIdx.y << 7;
  const int tid = threadIdx.x;
  const int tx = tid & 15, ty = tid >> 4;
  const int my = ty << 3, ox4 = tx << 2;
  __shared__ float smem[4096];
  float* sM = smem;
  float* sW = smem + 2048;
  float acc[8][8] = {};
  for (int cc = 0; cc < 256; cc += 16) {
    __syncthreads();
    stage16x128(sM, ET + (size_t)cc * M_ + m0, M_, tid);
    stage16x128(sW, w2T + (size_t)cc * 256 + o0, 256, tid);
    __syncthreads();
    gemm16s(sM, sW, my, ox4, acc);
  }
  #pragma unroll
  for (int mm = 0; mm < 8; ++mm) {
    const float4 v0 = {acc[mm][0], acc[mm][1], acc[mm][2], acc[mm][3]};
    const float4 v1 = {acc[mm][4], acc[mm][5], acc[mm][6], acc[mm][7]};
    float* dst = P + (size_t)(m0 + my + mm) * 256 + o0;
    *(float4*)(dst + ox4) = v0;
    *(float4*)(dst + ox4 + 64) = v1;
  }
}

// ---------------- fused dist+softmax: dm never materialized ----------------
// Block: 32 rows x full M=1024, 4 waves; wave w owns rows r0+8w..+7.
// Lane holds m = (lane<<2) + (q<<8) + jj -- identical to r4 k_soft's mapping.
// GEMM accumulation: fmaf chain over c=0..255 ascending -> dm bits identical
// to the passing r4/r6 runs -> argmax/hist/idx outputs bit-identical.
// FIX vs r6: the softmax row loop is fully unrolled so acc[][] is never
// runtime-indexed (rule #20) -- r6's 112-VGPR + 2.2 GB scratch-write spill.
__global__ __launch_bounds__(256, 2) void k_dsoft(const float* __restrict__ curT,
                                                  const float* __restrict__ ET,
                                                  const float* __restrict__ cur2,
                                                  const float* __restrict__ esq,
                                                  const float* __restrict__ gu,
                                                  float* __restrict__ soft4,
                                                  unsigned* __restrict__ hist,
                                                  int* __restrict__ idxi,
                                                  float* __restrict__ idxf) {
  const int tid = threadIdx.x;
  const int lane = tid & 63, wv = tid >> 6;
  const int r0 = blockIdx.x << 5;
  __shared__ float sC[16 * 32];      // [c][r]
  __shared__ float sE[16 * 1024];    // [c][m]
  __shared__ float accS[1024];
  __shared__ unsigned histS[1024];
  for (int j = tid; j < 1024; j += 256) { accS[j] = 0.f; histS[j] = 0u; }

  float acc[8][16];                  // [rr][s]; m = (lane<<2)+((s>>2)<<8)+(s&3)
  #pragma unroll
  for (int rr = 0; rr < 8; ++rr)
    #pragma unroll
    for (int s = 0; s < 16; ++s) acc[rr][s] = 0.f;

  for (int cc = 0; cc < 256; cc += 16) {
    __syncthreads();
    if (tid < 128) {
      const int c = tid >> 3, o = (tid & 7) << 2;
      *(float4*)&sC[c * 32 + o] = *(const float4*)&curT[(size_t)(cc + c) * NROW_ + r0 + o];
    }
    #pragma unroll
    for (int p = 0; p < 16; ++p) {
      const int q = p * 256 + tid;
      const int c = q >> 8, m = (q & 255) << 2;
      *(float4*)&sE[c * 1024 + m] = *(const float4*)&ET[(size_t)(cc + c) * M_ + m];
    }
    __syncthreads();
    #pragma unroll 4
    for (int c = 0; c < 16; ++c) {
      float a[8];
      *(float4*)&a[0] = *(const float4*)&sC[c * 32 + (wv << 3)];
      *(float4*)&a[4] = *(const float4*)&sC[c * 32 + (wv << 3) + 4];
      float bb[16];
      #pragma unroll
      for (int q = 0; q < 4; ++q)
        *(float4*)&bb[q << 2] = *(const float4*)&sE[c * 1024 + (q << 8) + (lane << 2)];
      #pragma unroll
      for (int rr = 0; rr < 8; ++rr)
        #pragma unroll
        for (int s = 0; s < 16; ++s)
          acc[rr][s] = fmaf(a[rr], bb[s], acc[rr][s]);
    }
  }

  // per-lane esq values (same m mapping)
  float e2v[16];
  #pragma unroll
  for (int q = 0; q < 4; ++q)
    *(float4*)&e2v[q << 2] = *(const float4*)&esq[(q << 8) + (lane << 2)];

  float p[16] = {};
  const int rbase = r0 + (wv << 3);
  #pragma unroll
  for (int rr = 0; rr < 8; ++rr) {
    const int r = rbase + rr;
    const float c2r = cur2[r];
    float v[16];
    #pragma unroll
    for (int s = 0; s < 16; ++s)
      v[s] = -(c2r + e2v[s] - 2.0f * acc[rr][s]);
    float mx = v[0];
    #pragma unroll
    for (int s = 1; s < 16; ++s) mx = fmaxf(mx, v[s]);
    #pragma unroll
    for (int m = 32; m; m >>= 1) mx = fmaxf(mx, __shfl_xor(mx, m, 64));
    float e[16]; float sum = 0.f;
    #pragma unroll
    for (int s = 0; s < 16; ++s) { e[s] = expf(v[s] - mx); sum += e[s]; }
    #pragma unroll
    for (int m = 32; m; m >>= 1) sum += __shfl_xor(sum, m, 64);
    const float inv = 1.0f / sum;
    #pragma unroll
    for (int s = 0; s < 16; ++s) p[s] = fmaf(e[s], inv, p[s]);
    float bv = v[0]; int bi = (lane << 2);
    #pragma unroll
    for (int s = 1; s < 16; ++s) {
      const int m_ = (lane << 2) + ((s >> 2) << 8) + (s & 3);
      if (v[s] > bv) { bv = v[s]; bi = m_; }
    }
    #pragma unroll
    for (int m = 32; m; m >>= 1) {
      const float ov = __shfl_xor(bv, m, 64);
      const int oi = __shfl_xor(bi, m, 64);
      if (ov > bv || (ov == bv && oi < bi)) { bv = ov; bi = oi; }
    }
    if (lane == 0) atomicAdd(&histS[bi], 1u);
    const float4* gr = (const float4*)(gu + ((size_t)r << 10));
    float z[16];
    #pragma unroll
    for (int k = 0; k < 4; ++k) {
      const float4 u = gr[lane + (k << 6)];
      const float uu[4] = {u.x, u.y, u.z, u.w};
      #pragma unroll
      for (int j = 0; j < 4; ++j) {
        const float uc = fminf(fmaxf(uu[j], 1e-10f), 1.0f - 1e-7f);
        z[k * 4 + j] = v[k * 4 + j] - logf(-logf(uc));
      }
    }
    bv = z[0]; bi = (lane << 2);
    #pragma unroll
    for (int s = 1; s < 16; ++s) {
      const int m_ = (lane << 2) + ((s >> 2) << 8) + (s & 3);
      if (z[s] > bv) { bv = z[s]; bi = m_; }
    }
    #pragma unroll
    for (int m = 32; m; m >>= 1) {
      const float ov = __shfl_xor(bv, m, 64);
      const int oi = __shfl_xor(bi, m, 64);
      if (ov > bv || (ov == bv && oi < bi)) { bv = ov; bi = oi; }
    }
    if (lane == 0) { idxi[r] = bi; idxf[r] = (float)bi; }
  }
  #pragma unroll
  for (int s = 0; s < 16; ++s)
    atomicAdd(&accS[(lane << 2) + ((s >> 2) << 8) + (s & 3)], p[s]);
  __syncthreads();
  const int rep = (blockIdx.x & 3) << 10;
  for (int j = tid; j < 1024; j += 256) {
    atomicAdd(&soft4[rep + j], accS[j]);
    const unsigned h = histS[j];
    if (h) atomicAdd(&hist[j], h);
  }
}

// ---------------- perplexities ----------------
__global__ __launch_bounds__(256) void k_perp(const float* __restrict__ soft4,
                                              const unsigned* __restrict__ hist,
                                              float* __restrict__ out2) {
  const int tid = threadIdx.x;
  float cp = 0.f, pp = 0.f;
  for (int m = tid; m < 1024; m += 256) {
    const float hp = (float)hist[m] * (1.0f / 32768.0f);
    cp += hp * log2f(hp + 1e-10f);
    const float q = (soft4[m] + soft4[1024 + m] + soft4[2048 + m] + soft4[3072 + m]) * (1.0f / 32768.0f);
    pp += q * log2f(q + 1e-10f);
  }
  #pragma unroll
  for (int off = 32; off; off >>= 1) {
    cp += __shfl_down(cp, off, 64);
    pp += __shfl_down(pp, off, 64);
  }
  __shared__ float rc[4], rp[4];
  const int lane = tid & 63, wv = tid >> 6;
  if (lane == 0) { rc[wv] = cp; rp[wv] = pp; }
  __syncthreads();
  if (tid == 0) {
    out2[0] = -((rc[0] + rc[1]) + (rc[2] + rc[3]));
    out2[1] = -((rp[0] + rp[1]) + (rp[2] + rp[3]));
  }
}

// ---------------- fuse2 via 1-plane bf16 MFMA ----------------
__global__ __launch_bounds__(256) void k_fuse2m(const float* __restrict__ ctxo,
                                                const float* __restrict__ w2T,
                                                const float* __restrict__ P,
                                                const int* __restrict__ idxi,
                                                const float* __restrict__ a2,
                                                float* __restrict__ outq) {
  const int bk = blockIdx.x;
  const int b = bk >> 6;
  const int t0 = (bk & 63) << 6;
  const int tid = threadIdx.x;
  const int lane = tid & 63, wv = tid >> 6;
  const int ln = lane & 15, lg = lane >> 4;
  const int o0w = wv << 6;
  __shared__ int idxS[64];
  if (tid < 64) idxS[tid] = idxi[(size_t)b * T_ + t0 + tid];
  __syncthreads();

  const f32x4 fz = {0.f, 0.f, 0.f, 0.f};
  f32x4 acc[4][4];   // [to][tt]
  #pragma unroll
  for (int i = 0; i < 4; ++i)
    #pragma unroll
    for (int j = 0; j < 4; ++j) acc[i][j] = fz;

  #pragma unroll 1
  for (int ks = 0; ks < 8; ++ks) {
    const int cb = (ks << 5) + (lg << 3);
    s16x8 Af[4];
    #pragma unroll
    for (int to = 0; to < 4; ++to) {
      const float* wp = w2T + (size_t)(256 + cb) * 256 + o0w + (to << 4) + ln;
      #pragma unroll
      for (int e = 0; e < 8; ++e)
        Af[to][e] = (short)bf16rne(wp[(size_t)e * 256]);
    }
    s16x8 Bf[4];
    #pragma unroll
    for (int tt = 0; tt < 4; ++tt) {
      const float* xp = ctxo + ((size_t)b * D_ + cb) * T_ + t0 + (tt << 4) + ln;
      #pragma unroll
      for (int e = 0; e < 8; ++e)
        Bf[tt][e] = (short)bf16rne(xp[(size_t)e * T_]);
    }
    #pragma unroll
    for (int to = 0; to < 4; ++to)
      #pragma unroll
      for (int tt = 0; tt < 4; ++tt)
        acc[to][tt] = __builtin_amdgcn_mfma_f32_16x16x32_bf16(Af[to], Bf[tt], acc[to][tt], 0, 0, 0);
  }

  const float alpha = a2[0];
  #pragma unroll
  for (int tt = 0; tt < 4; ++tt) {
    const int t = t0 + (tt << 4) + ln;
    const int id = idxS[(tt << 4) + ln];
    #pragma unroll
    for (int to = 0; to < 4; ++to) {
      const int ob = o0w + (to << 4) + (lg << 2);
      const float4 p4 = *(const float4*)&P[(size_t)id * 256 + ob];
      const float pv[4] = {p4.x, p4.y, p4.z, p4.w};
      float o[4];
      #pragma unroll
      for (int rg = 0; rg < 4; ++rg) {
        const float v = acc[to][tt][rg] + pv[rg];
        o[rg] = (v >= 0.f) ? v : alpha * v;
      }
      *(float4*)&outq[((size_t)b * T_ + t) * D_ + ob] = *(float4*)&o[0];
    }
  }
}

extern "C" void kernel_launch(void* const* d_in, const int* in_sizes, int n_in,
                              void* d_out, int out_size, void* d_ws, size_t ws_size,
                              hipStream_t stream) {
  (void)in_sizes; (void)n_in; (void)out_size; (void)ws_size;
  const float* x     = (const float*)d_in[0];
  const float* noise = (const float*)d_in[1];
  const float* gu    = (const float*)d_in[2];
  const int*   epo   = (const int*)d_in[3];
  const float* emb   = (const float*)d_in[4];
  const float* wctx  = (const float*)d_in[5];
  const float* wf1   = (const float*)d_in[6];
  const float* a1    = (const float*)d_in[7];
  const float* wf2   = (const float*)d_in[8];
  const float* a2    = (const float*)d_in[9];

  float* ws    = (float*)d_ws;
  float* xT    = ws + OFF_XT;
  ushort* inT  = (ushort*)(ws + OFF_CTXN);
  float* curT  = ws + OFF_CURT;
  float* ctxo  = ws + OFF_CTXO;
  float* cur2  = ws + OFF_CUR2;
  float* soft  = ws + OFF_SOFT;
  unsigned* hist = (unsigned*)(ws + OFF_HIST);
  float* sumsq = ws + OFF_SUMSQ;
  float* esq   = ws + OFF_ESQ;
  int*   idxi  = (int*)(ws + OFF_IDX);
  float* ET    = ws + OFF_ET;
  float* W1T   = ws + OFF_W1T;
  float* W2T   = ws + OFF_W2T;
  ushort* WPF  = (ushort*)(ws + OFF_WCT);
  float* P     = ws + OFF_P;

  float* outq = (float*)d_out;
  float* scal = outq + (size_t)NROW_ * D_;
  float* idxf = scal + 2;

  hipMemsetAsync(ws + OFF_CUR2, 0, (NROW_ + 4096 + 1024 + 16) * sizeof(float), stream);

  k_prep  <<<1504, 256, 0, stream>>>(emb, wf1, wf2, wctx, x, ET, W1T, W2T, WPF, esq, sumsq);
  k_noisy <<<dim3(129, 8, 8), 256, 0, stream>>>(x, noise, epo, sumsq, inT, xT);
  k_convm <<<dim3(64, 8), 256, 0, stream>>>(WPF, inT, ctxo);
  k_fuse1 <<<dim3(256, 2), 256, 0, stream>>>(xT, ctxo, W1T, a1, curT, cur2);
  k_pmm   <<<dim3(8, 2), 256, 0, stream>>>(ET, W2T, P);
  k_dsoft <<<1024, 256, 0, stream>>>(curT, ET, cur2, esq, gu, soft, hist, idxi, idxf);
  k_perp  <<<1, 256, 0, stream>>>(soft, hist, scal);
  k_fuse2m<<<512, 256, 0, stream>>>(ctxo, W2T, P, idxi, a2, outq);
}